// Round 7
// baseline (549.371 us; speedup 1.0000x reference)
//
#include <hip/hip_runtime.h>
#include <hip/hip_bf16.h>

#define NSITES 100000
#define KOFFS 27
#define CIN 64
#define COUT 128
#define NHALF 50048                        // half0 sites [0,50048), half1 [50048,100000)
#define PSTRIDE_E ((NSITES + 8) * 16)      // u16 elems per 16-ch plane (3,200,256 B, 128B-mult)

typedef unsigned short u16;
typedef __attribute__((ext_vector_type(8))) short s16x8;
typedef __attribute__((ext_vector_type(4))) float f32x4;

static __device__ __forceinline__ u16 f2bf(float f) {
    union { float f; unsigned u; } x; x.f = f;
    return (u16)((x.u + 0x7FFFu + ((x.u >> 16) & 1u)) >> 16);
}
static __device__ __forceinline__ float bf2f(u16 v) {
    union { unsigned u; float f; } x; x.u = ((unsigned)v) << 16;
    return x.f;
}

// LDS-only barrier: does NOT drain vmcnt (keeps gather prefetch in flight).
static __device__ __forceinline__ void lds_barrier() {
    __asm__ __volatile__("s_waitcnt lgkmcnt(0)\n\ts_barrier" ::: "memory");
}

// ---------- prep: W1t [27][128][64]; W2t [27][128][128] (fallback); W2p [8][14][128][32]
// (paired-k, zero-pad k=27); Wskt [128][64]; zero stat partials ----------
__global__ void prep_kernel(const float* __restrict__ W1, const float* __restrict__ W2,
                            const float* __restrict__ Wsk, u16* __restrict__ W1t,
                            u16* __restrict__ W2t, u16* __restrict__ W2p,
                            u16* __restrict__ Wskt, float* __restrict__ zero_area) {
    int i = blockIdx.x * 256 + threadIdx.x;
    if (i < 221184) {
        int k = i / 8192, r = i & 8191, d = r >> 6, c = r & 63;
        W1t[i] = f2bf(W1[k * 8192 + c * 128 + d]);
        return;
    }
    i -= 221184;
    if (i < 442368) {
        int k = i / 16384, r = i & 16383, d = r >> 7, c = r & 127;
        W2t[i] = f2bf(W2[k * 16384 + c * 128 + d]);
        return;
    }
    i -= 442368;
    if (i < 458752) {  // W2p: i=((g*14+s)*128+d)*32+j ; j<16 -> k=2s,c=16g+j ; else k=2s+1
        int j = i & 31, t = i >> 5;
        int d = t & 127; t >>= 7;
        int s = t % 14, g = t / 14;
        int k = 2 * s + (j >> 4);
        int c = 16 * g + (j & 15);
        W2p[i] = (k < 27) ? f2bf(W2[k * 16384 + c * 128 + d]) : (u16)0;
        return;
    }
    i -= 458752;
    if (i < 8192) {
        int d = i >> 6, c = i & 63;
        Wskt[i] = f2bf(Wsk[c * 128 + d]);
        return;
    }
    i -= 8192;
    if (i < 32768) zero_area[i] = 0.0f;
}

// ---------- x (fp32) -> bf16 rows, plus zero sentinel row N ----------
__global__ void convert_x_kernel(const float* __restrict__ x, u16* __restrict__ xb) {
    long long e = ((long long)blockIdx.x * 256 + threadIdx.x) * 8;
    if (e >= (long long)(NSITES + 1) * CIN) return;
    s16x8 o;
    if (e < (long long)NSITES * CIN) {
        float4 v0 = *(const float4*)(x + e);
        float4 v1 = *(const float4*)(x + e + 4);
        o[0] = (short)f2bf(v0.x); o[1] = (short)f2bf(v0.y);
        o[2] = (short)f2bf(v0.z); o[3] = (short)f2bf(v0.w);
        o[4] = (short)f2bf(v1.x); o[5] = (short)f2bf(v1.y);
        o[6] = (short)f2bf(v1.z); o[7] = (short)f2bf(v1.w);
    } else {
#pragma unroll
        for (int j = 0; j < 8; ++j) o[j] = 0;
    }
    *(s16x8*)(xb + e) = o;
}

// ---------- R6 gather-GEMM (conv1 + fallback conv2): dbuf LDS, lds_barrier, dist-2 gathers ----
template <int CK, bool IDENT_FUSE, bool STATS, int OCC>
__global__ __launch_bounds__(256, OCC) void conv_kernel(
    const u16* __restrict__ xin, const int* __restrict__ nbr,
    const u16* __restrict__ Wt, u16* __restrict__ yout,
    float* __restrict__ psum, float* __restrict__ psq, int nk,
    const u16* __restrict__ Wskt, float* __restrict__ outid) {
    constexpr int KSTEPS = CK / 32;
    constexpr int CPR = CK / 8;
    constexpr int SWZ = CPR - 1;
    constexpr int RPP = 256 / CPR;
    constexpr int NPASS = 64 / RPP;
    __shared__ __align__(16) u16 a_tile[2][64 * CK];

    const int tid = threadIdx.x;
    const int wave = tid >> 6;
    const int lane = tid & 63;
    const int m = lane & 15;
    const int q = lane >> 4;
    const int n0 = blockIdx.x * 64;
    const int wc = wave * 32;
    const int srow = tid / CPR;
    const int schunk = tid % CPR;

    f32x4 acc[4][2];
#pragma unroll
    for (int rt = 0; rt < 4; ++rt)
#pragma unroll
        for (int ct = 0; ct < 2; ++ct)
#pragma unroll
            for (int r = 0; r < 4; ++r) acc[rt][ct][r] = 0.0f;

    int nidx0[NPASS], nidx1[NPASS], tmp[NPASS];
    s16x8 ag0[NPASS], ag1[NPASS];
#pragma unroll
    for (int p = 0; p < NPASS; ++p) {
        int row = n0 + p * RPP + srow;
        tmp[p] = (row < NSITES) ? nbr[row * KOFFS] : NSITES;
    }
#pragma unroll
    for (int p = 0; p < NPASS; ++p)
        ag0[p] = *(const s16x8*)(xin + (long long)tmp[p] * CK + schunk * 8);
#pragma unroll
    for (int p = 0; p < NPASS; ++p) {
        int row = n0 + p * RPP + srow;
        tmp[p] = (row < NSITES && nk > 1) ? nbr[row * KOFFS + 1] : NSITES;
    }
#pragma unroll
    for (int p = 0; p < NPASS; ++p)
        ag1[p] = *(const s16x8*)(xin + (long long)tmp[p] * CK + schunk * 8);
#pragma unroll
    for (int p = 0; p < NPASS; ++p) {
        int row = n0 + p * RPP + srow;
        nidx0[p] = (row < NSITES && nk > 2) ? nbr[row * KOFFS + 2] : NSITES;
        nidx1[p] = (row < NSITES && nk > 3) ? nbr[row * KOFFS + 3] : NSITES;
    }
#pragma unroll
    for (int p = 0; p < NPASS; ++p) {
        int r = p * RPP + srow;
        *(s16x8*)(a_tile[0] + r * CK + ((schunk ^ (r & SWZ)) * 8)) = ag0[p];
    }
    __syncthreads();

    auto stage = [&](int k, s16x8 (&g_in)[NPASS], int (&idx_in)[NPASS],
                     s16x8 (&g_out)[NPASS], const u16* abuf, u16* wbuf) {
        s16x8 bf[2][KSTEPS];
        const u16* wb = Wt + (long long)k * (COUT * CK);
#pragma unroll
        for (int ct = 0; ct < 2; ++ct)
#pragma unroll
            for (int ks = 0; ks < KSTEPS; ++ks)
                bf[ct][ks] = *(const s16x8*)(wb + (wc + ct * 16 + m) * CK + ks * 32 + q * 8);

        if (k + 2 < nk) {
#pragma unroll
            for (int p = 0; p < NPASS; ++p)
                g_in[p] = *(const s16x8*)(xin + (long long)idx_in[p] * CK + schunk * 8);
        }
#pragma unroll
        for (int p = 0; p < NPASS; ++p) {
            int row = n0 + p * RPP + srow;
            idx_in[p] = (row < NSITES && k + 4 < nk) ? nbr[row * KOFFS + k + 4] : NSITES;
        }

#pragma unroll
        for (int ks = 0; ks < KSTEPS; ++ks) {
            s16x8 af[4];
#pragma unroll
            for (int rt = 0; rt < 4; ++rt) {
                int r = rt * 16 + m;
                af[rt] = *(const s16x8*)(abuf + r * CK + (((ks * 4 + q) ^ (r & SWZ)) * 8));
            }
#pragma unroll
            for (int rt = 0; rt < 4; ++rt)
#pragma unroll
                for (int ct = 0; ct < 2; ++ct)
                    acc[rt][ct] = __builtin_amdgcn_mfma_f32_16x16x32_bf16(
                        af[rt], bf[ct][ks], acc[rt][ct], 0, 0, 0);
        }

        if (k + 1 < nk) {
#pragma unroll
            for (int p = 0; p < NPASS; ++p) {
                int r = p * RPP + srow;
                *(s16x8*)(wbuf + r * CK + ((schunk ^ (r & SWZ)) * 8)) = g_out[p];
            }
        }
        lds_barrier();
    };

    for (int k = 0; k < nk; k += 2) {
        stage(k, ag0, nidx0, ag1, a_tile[0], a_tile[1]);
        if (k + 1 < nk) stage(k + 1, ag1, nidx1, ag0, a_tile[1], a_tile[0]);
    }

#pragma unroll
    for (int rt = 0; rt < 4; ++rt) {
        int rowb = n0 + rt * 16 + q * 4;
#pragma unroll
        for (int ct = 0; ct < 2; ++ct) {
            int col = wc + ct * 16 + m;
#pragma unroll
            for (int r = 0; r < 4; ++r) {
                int row = rowb + r;
                if (row < NSITES) yout[(long long)row * COUT + col] = f2bf(acc[rt][ct][r]);
            }
        }
    }

    if (STATS) {
#pragma unroll
        for (int ct = 0; ct < 2; ++ct) {
            float s = 0.f, ss = 0.f;
#pragma unroll
            for (int rt = 0; rt < 4; ++rt)
#pragma unroll
                for (int r = 0; r < 4; ++r) {
                    float v = acc[rt][ct][r];
                    s += v; ss += v * v;
                }
            s += __shfl_xor(s, 16); ss += __shfl_xor(ss, 16);
            s += __shfl_xor(s, 32); ss += __shfl_xor(ss, 32);
            if (q == 0) {
                int col = wc + ct * 16 + m;
                int slot = blockIdx.x & 63;
                atomicAdd(psum + slot * COUT + col, s);
                atomicAdd(psq + slot * COUT + col, ss);
            }
        }
    }

    if (IDENT_FUSE) {
#pragma unroll
        for (int rt = 0; rt < 4; ++rt)
#pragma unroll
            for (int ct = 0; ct < 2; ++ct)
#pragma unroll
                for (int r = 0; r < 4; ++r) acc[rt][ct][r] = 0.0f;
        s16x8 aid[NPASS];
#pragma unroll
        for (int p = 0; p < NPASS; ++p) {
            int row = n0 + p * RPP + srow;
            long long idx = (row < NSITES) ? row : NSITES;
            aid[p] = *(const s16x8*)(xin + idx * CK + schunk * 8);
        }
        s16x8 bfi[2][KSTEPS];
#pragma unroll
        for (int ct = 0; ct < 2; ++ct)
#pragma unroll
            for (int ks = 0; ks < KSTEPS; ++ks)
                bfi[ct][ks] = *(const s16x8*)(Wskt + (wc + ct * 16 + m) * CK + ks * 32 + q * 8);
#pragma unroll
        for (int p = 0; p < NPASS; ++p) {
            int r = p * RPP + srow;
            *(s16x8*)(a_tile[0] + r * CK + ((schunk ^ (r & SWZ)) * 8)) = aid[p];
        }
        __syncthreads();
#pragma unroll
        for (int ks = 0; ks < KSTEPS; ++ks) {
            s16x8 af[4];
#pragma unroll
            for (int rt = 0; rt < 4; ++rt) {
                int r = rt * 16 + m;
                af[rt] = *(const s16x8*)(a_tile[0] + r * CK + (((ks * 4 + q) ^ (r & SWZ)) * 8));
            }
#pragma unroll
            for (int rt = 0; rt < 4; ++rt)
#pragma unroll
                for (int ct = 0; ct < 2; ++ct)
                    acc[rt][ct] = __builtin_amdgcn_mfma_f32_16x16x32_bf16(
                        af[rt], bfi[ct][ks], acc[rt][ct], 0, 0, 0);
        }
#pragma unroll
        for (int rt = 0; rt < 4; ++rt) {
            int rowb = n0 + rt * 16 + q * 4;
#pragma unroll
            for (int ct = 0; ct < 2; ++ct) {
                int col = wc + ct * 16 + m;
#pragma unroll
                for (int r = 0; r < 4; ++r) {
                    int row = rowb + r;
                    if (row < NSITES) outid[(long long)row * COUT + col] = acc[rt][ct][r];
                }
            }
        }
    }
}

// ---------- XCD-pinned channel-sharded conv2: group g = blockIdx&7 gathers ONLY its 3.2MB
// 16-ch plane (fits 4MB per-XCD L2 -> gathers become L2 hits, dodging the ~1.4TB/s
// random-miss ceiling). 14 stages of K=32 (2 k-offsets x 16ch). pp written with
// full-line NT stores via LDS transpose (no sub-line NT, no plane eviction). ----------
__global__ __launch_bounds__(256, 4) void conv2_sharded_kernel(
    const u16* __restrict__ hp, const int* __restrict__ nbr,
    const u16* __restrict__ W2p, u16* __restrict__ pp, int half_base) {
    __shared__ __align__(16) u16 a_tile[2][64 * 32];   // 2 x 4KB
    __shared__ __align__(16) u16 eld[32 * 128];        // 8KB epilogue staging

    const int bid = blockIdx.x;
    const int g = bid & 7;
    const int tile = bid >> 3;
    const u16* plane = hp + (long long)g * PSTRIDE_E;
    const u16* wbase = W2p + g * (14 * 128 * 32);

    const int tid = threadIdx.x;
    const int lane = tid & 63;
    const int wave = tid >> 6;
    const int m = lane & 15;
    const int q = lane >> 4;
    const int wc = wave * 32;
    const int n0 = half_base + tile * 64;
    const int r = tid >> 2;          // staging row 0..63
    const int p = tid & 3;           // ko = p>>1 (k-offset of pair), hs = p&1 (8-ch half)
    const int ko = p >> 1, hs = p & 1;
    const int myrow = n0 + r;
    const bool rv = myrow < NSITES;

    int nidx[14];
#pragma unroll
    for (int s = 0; s < 14; ++s) {
        int k = 2 * s + ko;
        nidx[s] = (rv && k < 27) ? nbr[myrow * KOFFS + k] : NSITES;
    }

    f32x4 acc[4][2];
#pragma unroll
    for (int rt = 0; rt < 4; ++rt)
#pragma unroll
        for (int ct = 0; ct < 2; ++ct)
#pragma unroll
            for (int rr = 0; rr < 4; ++rr) acc[rt][ct][rr] = 0.0f;

    {
        s16x8 a0 = *(const s16x8*)(plane + (long long)nidx[0] * 16 + hs * 8);
        *(s16x8*)(a_tile[0] + r * 32 + ((p ^ (r & 3)) * 8)) = a0;
    }
    __syncthreads();

#pragma unroll
    for (int s = 0; s < 14; ++s) {
        const u16* abuf = a_tile[s & 1];
        u16* wbuf = a_tile[(s + 1) & 1];

        s16x8 bf0 = *(const s16x8*)(wbase + (s * 128 + wc + m) * 32 + q * 8);
        s16x8 bf1 = *(const s16x8*)(wbase + (s * 128 + wc + 16 + m) * 32 + q * 8);

        s16x8 agn;
        if (s + 1 < 14)
            agn = *(const s16x8*)(plane + (long long)nidx[s + 1] * 16 + hs * 8);

        s16x8 af[4];
#pragma unroll
        for (int rt = 0; rt < 4; ++rt) {
            int rr = rt * 16 + m;
            af[rt] = *(const s16x8*)(abuf + rr * 32 + ((q ^ (rr & 3)) * 8));
        }
#pragma unroll
        for (int rt = 0; rt < 4; ++rt) {
            acc[rt][0] = __builtin_amdgcn_mfma_f32_16x16x32_bf16(af[rt], bf0, acc[rt][0], 0, 0, 0);
            acc[rt][1] = __builtin_amdgcn_mfma_f32_16x16x32_bf16(af[rt], bf1, acc[rt][1], 0, 0, 0);
        }

        if (s + 1 < 14)
            *(s16x8*)(wbuf + r * 32 + ((p ^ (r & 3)) * 8)) = agn;
        lds_barrier();
    }

    // epilogue: 2 halves of 32 rows through LDS -> full-line NT dwordx4 streams
    u16* ppg = pp + ((long long)g * NHALF + (long long)tile * 64) * 128;
#pragma unroll
    for (int h = 0; h < 2; ++h) {
#pragma unroll
        for (int rt = 2 * h; rt < 2 * h + 2; ++rt) {
#pragma unroll
            for (int ct = 0; ct < 2; ++ct) {
#pragma unroll
                for (int rr = 0; rr < 4; ++rr) {
                    int lrow = rt * 16 + q * 4 + rr - h * 32;  // 0..31
                    eld[lrow * 128 + wc + ct * 16 + m] = f2bf(acc[rt][ct][rr]);
                }
            }
        }
        __syncthreads();
        {
            int lrow = tid >> 3;
            int off = (tid & 7) * 16;  // u16 elems
            s16x8 v0 = *(const s16x8*)(eld + lrow * 128 + off);
            s16x8 v1 = *(const s16x8*)(eld + lrow * 128 + off + 8);
            u16* dst = ppg + (long long)(h * 32 + lrow) * 128 + off;
            __builtin_nontemporal_store(v0, (s16x8*)dst);
            __builtin_nontemporal_store(v1, (s16x8*)(dst + 8));
        }
        __syncthreads();
    }
}

// ---------- sum 8 group-partials -> y bf16 + BN2 stat partials ----------
__global__ void reduce2_kernel(const u16* __restrict__ pp, u16* __restrict__ y,
                               float* __restrict__ psum, float* __restrict__ psq,
                               int half_base, int nsites_half) {
    __shared__ float cs[128], cq[128];
    const int tid = threadIdx.x;
    if (tid < 128) { cs[tid] = 0.f; cq[tid] = 0.f; }
    __syncthreads();

    const int sl = blockIdx.x * 16 + (tid >> 4);
    const int ch0 = (tid & 15) * 8;
    float v[8];
#pragma unroll
    for (int j = 0; j < 8; ++j) v[j] = 0.f;
    if (sl < nsites_half) {
#pragma unroll
        for (int g = 0; g < 8; ++g) {
            s16x8 t = *(const s16x8*)(pp + ((long long)g * NHALF + sl) * 128 + ch0);
#pragma unroll
            for (int j = 0; j < 8; ++j) v[j] += bf2f((u16)t[j]);
        }
        s16x8 o;
#pragma unroll
        for (int j = 0; j < 8; ++j) o[j] = (short)f2bf(v[j]);
        *(s16x8*)(y + ((long long)(half_base + sl)) * 128 + ch0) = o;
    }
    float s[8], ss[8];
#pragma unroll
    for (int j = 0; j < 8; ++j) { s[j] = v[j]; ss[j] = v[j] * v[j]; }
#pragma unroll
    for (int j = 0; j < 8; ++j) {
        s[j] += __shfl_xor(s[j], 16); ss[j] += __shfl_xor(ss[j], 16);
        s[j] += __shfl_xor(s[j], 32); ss[j] += __shfl_xor(ss[j], 32);
    }
    if ((tid & 63) < 16) {
#pragma unroll
        for (int j = 0; j < 8; ++j) {
            atomicAdd(&cs[ch0 + j], s[j]);
            atomicAdd(&cq[ch0 + j], ss[j]);
        }
    }
    __syncthreads();
    if (tid < 128) {
        int slot = blockIdx.x & 63;
        atomicAdd(psum + slot * COUT + tid, cs[tid]);
        atomicAdd(psq + slot * COUT + tid, cq[tid]);
    }
}

// ---------- reduce 64 slots -> per-column affine ----------
__global__ void bn_stats_kernel(const float* __restrict__ psum, const float* __restrict__ psq,
                                const float* __restrict__ gamma, const float* __restrict__ beta,
                                float* __restrict__ ab) {
    int col = threadIdx.x;
    float s = 0.f, ss = 0.f;
    for (int i = 0; i < 64; ++i) { s += psum[i * COUT + col]; ss += psq[i * COUT + col]; }
    const float inv_n = 1.0f / (float)NSITES;
    float mu = s * inv_n;
    float var = ss * inv_n - mu * mu;
    float rs = rsqrtf(var + 1e-5f);
    float a = gamma[col] * rs;
    ab[col] = a;
    ab[COUT + col] = beta[col] - mu * a;
}

// ---------- BN1-apply -> sharded 16-ch planes, normal stores (+ zero sentinel row) ----------
__global__ void bn_apply_sharded_kernel(const u16* __restrict__ y, const float* __restrict__ ab,
                                        u16* __restrict__ hp) {
    int i = blockIdx.x * 256 + threadIdx.x;  // 8 * (N+1) * 2 half-slices
    if (i >= 8 * (NSITES + 1) * 2) return;
    int g = i / ((NSITES + 1) * 2);
    int rem = i - g * ((NSITES + 1) * 2);
    int r = rem >> 1, half = rem & 1;
    int ch0 = 16 * g + 8 * half;
    s16x8 o;
    if (r < NSITES) {
        s16x8 v = *(const s16x8*)(y + (long long)r * 128 + ch0);
#pragma unroll
        for (int j = 0; j < 8; ++j) {
            float t = bf2f((u16)v[j]) * ab[ch0 + j] + ab[COUT + ch0 + j];
            o[j] = (short)f2bf(fmaxf(t, 0.f));
        }
    } else {
#pragma unroll
        for (int j = 0; j < 8; ++j) o[j] = 0;
    }
    *(s16x8*)(hp + (long long)g * PSTRIDE_E + (long long)r * 16 + half * 8) = o;
}

// ---------- unsharded BN1-apply (fallback) ----------
__global__ void bn_apply_kernel(const u16* __restrict__ y, const float* __restrict__ ab,
                                u16* __restrict__ h) {
    long long e = ((long long)blockIdx.x * 256 + threadIdx.x) * 8;
    if (e >= (long long)(NSITES + 1) * COUT) return;
    s16x8 o;
    if (e < (long long)NSITES * COUT) {
        int cb = (int)(e & (COUT - 1));
        s16x8 v = *(const s16x8*)(y + e);
#pragma unroll
        for (int j = 0; j < 8; ++j) {
            float r = bf2f((u16)v[j]) * ab[cb + j] + ab[COUT + cb + j];
            o[j] = (short)f2bf(fmaxf(r, 0.f));
        }
    } else {
#pragma unroll
        for (int j = 0; j < 8; ++j) o[j] = 0;
    }
    *(s16x8*)(h + e) = o;
}

// ---------- out = relu(y*a+b) + identity ----------
__global__ void final_kernel(const u16* __restrict__ y, const float* __restrict__ ab,
                             float* __restrict__ out) {
    long long e = ((long long)blockIdx.x * 256 + threadIdx.x) * 8;
    if (e >= (long long)NSITES * COUT) return;
    int cb = (int)(e & (COUT - 1));
    s16x8 v = *(const s16x8*)(y + e);
    float4 i0 = *(const float4*)(out + e);
    float4 i1 = *(const float4*)(out + e + 4);
    float is[8] = {i0.x, i0.y, i0.z, i0.w, i1.x, i1.y, i1.z, i1.w};
    float os[8];
#pragma unroll
    for (int j = 0; j < 8; ++j) {
        float r = bf2f((u16)v[j]) * ab[cb + j] + ab[COUT + cb + j];
        os[j] = fmaxf(r, 0.f) + is[j];
    }
    *(float4*)(out + e) = make_float4(os[0], os[1], os[2], os[3]);
    *(float4*)(out + e + 4) = make_float4(os[4], os[5], os[6], os[7]);
}

extern "C" void kernel_launch(void* const* d_in, const int* in_sizes, int n_in,
                              void* d_out, int out_size, void* d_ws, size_t ws_size,
                              hipStream_t stream) {
    const float* x   = (const float*)d_in[0];
    const int*   nbr = (const int*)d_in[1];
    const float* W1  = (const float*)d_in[2];
    const float* g1  = (const float*)d_in[3];
    const float* b1  = (const float*)d_in[4];
    const float* W2  = (const float*)d_in[5];
    const float* g2  = (const float*)d_in[6];
    const float* b2  = (const float*)d_in[7];
    const float* Wsk = (const float*)d_in[8];
    float* out = (float*)d_out;

    // workspace layout (bytes); sharded total = 168,894,592 (R5 proved >=205MB available)
    char* ws = (char*)d_ws;
    u16*   xb   = (u16*)(ws);                    // 12,800,128
    u16*   W1t  = (u16*)(ws + 12800128);         //    442,368
    u16*   W2t  = (u16*)(ws + 13242496);         //    884,736  (fallback)
    u16*   Wskt = (u16*)(ws + 14127232);         //     16,384
    u16*   y    = (u16*)(ws + 14143616);         // 25,600,000
    u16*   hp   = (u16*)(ws + 39743616);         // 25,602,048 (8 planes; union w/ fallback h1)
    u16*   h1   = (u16*)(ws + 39743616);         // fallback alias
    float* ps1  = (float*)(ws + 65345664);       // stats 133,120
    float* pq1  = ps1 + 8192;
    float* ps2  = pq1 + 8192;
    float* pq2  = ps2 + 8192;
    float* ab1  = pq2 + 8192;
    float* ab2  = ab1 + 256;
    u16*   W2p  = (u16*)(ws + 65478784);         //    917,504
    u16*   pp   = (u16*)(ws + 66396288);         // 102,498,304 (8 x 50048 x 128 bf16)
    const size_t WS_NEED = 168894592ULL;

    const int NBLK = (NSITES + 63) / 64;  // 1563
    const bool sharded = (ws_size >= WS_NEED);

    prep_kernel<<<4544, 256, 0, stream>>>(W1, W2, Wsk, W1t, W2t, W2p, Wskt, ps1);
    convert_x_kernel<<<3126, 256, 0, stream>>>(x, xb);
    conv_kernel<64, true, true, 4><<<NBLK, 256, 0, stream>>>(xb, nbr, W1t, y, ps1, pq1, KOFFS, Wskt, out);
    bn_stats_kernel<<<1, 128, 0, stream>>>(ps1, pq1, g1, b1, ab1);

    if (sharded) {
        bn_apply_sharded_kernel<<<6251, 256, 0, stream>>>(y, ab1, hp);
        conv2_sharded_kernel<<<8 * 782, 256, 0, stream>>>(hp, nbr, W2p, pp, 0);
        reduce2_kernel<<<3128, 256, 0, stream>>>(pp, y, ps2, pq2, 0, 50048);
        conv2_sharded_kernel<<<8 * 781, 256, 0, stream>>>(hp, nbr, W2p, pp, NHALF);
        reduce2_kernel<<<3122, 256, 0, stream>>>(pp, y, ps2, pq2, NHALF, NSITES - NHALF);
    } else {
        bn_apply_kernel<<<6251, 256, 0, stream>>>(y, ab1, h1);
        conv_kernel<128, false, true, 3><<<NBLK, 256, 0, stream>>>(h1, nbr, W2t, y, ps2, pq2, KOFFS,
                                                                   nullptr, nullptr);
    }
    bn_stats_kernel<<<1, 128, 0, stream>>>(ps2, pq2, g2, b2, ab2);
    final_kernel<<<6250, 256, 0, stream>>>(y, ab2, out);
}